// Round 4
// baseline (786.745 us; speedup 1.0000x reference)
//
#include <hip/hip_runtime.h>

#define S_LEN 2048
#define HID 4096
#define NH 32
#define HD 128
#define QKV_N 12288   // 3*HID

typedef __attribute__((ext_vector_type(8))) short bf16x8;
typedef __attribute__((ext_vector_type(4))) float f32x4;

__device__ __forceinline__ unsigned short f2bf(float f) {
    unsigned int u = __float_as_uint(f);
    u += 0x7FFF + ((u >> 16) & 1);
    return (unsigned short)(u >> 16);
}
__device__ __forceinline__ float bf2f(unsigned short h) {
    return __uint_as_float(((unsigned int)h) << 16);
}

typedef __attribute__((address_space(1))) const void gconst_void;
typedef __attribute__((address_space(3))) void lds_void;
__device__ __forceinline__ void gl16(const void* g, void* l) {
    __builtin_amdgcn_global_load_lds((gconst_void*)g, (lds_void*)l, 16, 0, 0);
}

#define VMCNT(n) asm volatile("s_waitcnt vmcnt(" #n ")" ::: "memory")
#define LGKM0()  asm volatile("s_waitcnt lgkmcnt(0)" ::: "memory")
#define BAR()    do { asm volatile("" ::: "memory"); __builtin_amdgcn_s_barrier(); asm volatile("" ::: "memory"); } while (0)

// ---------------- fp32 -> bf16 linear convert ----------------
__global__ __launch_bounds__(256)
void cvt_f32_bf16(const float* __restrict__ in, unsigned short* __restrict__ out, int n8)
{
    int i = blockIdx.x * 256 + threadIdx.x;
    if (i >= n8) return;
    const float4* p = (const float4*)in + (size_t)i * 2;
    float4 a = p[0], b = p[1];
    bf16x8 o;
    o[0] = (short)f2bf(a.x); o[1] = (short)f2bf(a.y); o[2] = (short)f2bf(a.z); o[3] = (short)f2bf(a.w);
    o[4] = (short)f2bf(b.x); o[5] = (short)f2bf(b.y); o[6] = (short)f2bf(b.z); o[7] = (short)f2bf(b.w);
    *((bf16x8*)out + i) = o;
}

// ---------------- fp32 [K][N] -> bf16 [N][K] transpose-convert ----------------
__global__ __launch_bounds__(256)
void cvt_w_t(const float* __restrict__ W, unsigned short* __restrict__ Wt, int N, int K)
{
    __shared__ unsigned short t[64][72];
    const int tid = threadIdx.x;
    const int n0 = blockIdx.x * 64, k0 = blockIdx.y * 64;
    const int c4 = (tid & 15) * 4;
    const int r  = tid >> 4;
    #pragma unroll
    for (int p = 0; p < 4; ++p) {
        float4 v = *(const float4*)&W[(size_t)(k0 + r + p * 16) * N + n0 + c4];
        ushort4 o;
        o.x = f2bf(v.x); o.y = f2bf(v.y); o.z = f2bf(v.z); o.w = f2bf(v.w);
        *(ushort4*)&t[r + p * 16][c4] = o;
    }
    __syncthreads();
    const int n = tid >> 2;
    const int kq = (tid & 3) * 16;
    unsigned short* dst = &Wt[(size_t)(n0 + n) * K + k0 + kq];
    bf16x8 v0, v1;
    #pragma unroll
    for (int j = 0; j < 8; ++j) v0[j] = (short)t[kq + j][n];
    #pragma unroll
    for (int j = 0; j < 8; ++j) v1[j] = (short)t[kq + 8 + j][n];
    *(bf16x8*)dst = v0;
    *(bf16x8*)(dst + 8) = v1;
}

// ---------------- bf16 V slab [s][c] -> Vtg [c][s] transpose ----------------
__global__ __launch_bounds__(256)
void v_transpose(const unsigned short* __restrict__ QKV, unsigned short* __restrict__ Vtg)
{
    __shared__ unsigned short t[64][72];
    const int tid = threadIdx.x;
    const int s0 = blockIdx.x * 64;   // seq tile
    const int c0 = blockIdx.y * 64;   // channel tile (c = h*128+d)
    #pragma unroll
    for (int i = 0; i < 2; ++i) {
        int idx = i * 256 + tid;
        int r = idx >> 3, c8 = (idx & 7) * 8;
        *(bf16x8*)&t[r][c8] = *(const bf16x8*)&QKV[(size_t)(s0 + r) * QKV_N + 2 * HID + c0 + c8];
    }
    __syncthreads();
    #pragma unroll
    for (int i = 0; i < 2; ++i) {
        int idx = i * 256 + tid;
        int oc = idx >> 3, os8 = (idx & 7) * 8;
        bf16x8 v;
        #pragma unroll
        for (int j = 0; j < 8; ++j) v[j] = (short)t[os8 + j][oc];
        *(bf16x8*)&Vtg[(size_t)(c0 + oc) * S_LEN + s0 + os8] = v;
    }
}

// ---------------- 256x256 8-phase GEMM: C = A[M,K] * Bt[N,K]^T ----------------
__device__ __forceinline__ void lda4(bf16x8 af[4][2], const char* base, int rq, int l15, int lg) {
    const int sw = (l15 & 7) << 4;
    #pragma unroll
    for (int i = 0; i < 4; ++i) {
        const char* rb = base + ((rq * 4 + i) * 16 + l15) * 128;
        af[i][0] = *(const bf16x8*)(rb + ((lg * 16) ^ sw));
        af[i][1] = *(const bf16x8*)(rb + ((64 + lg * 16) ^ sw));
    }
}
__device__ __forceinline__ void ldb2(bf16x8 bf[2][2], const char* base, int cq, int l15, int lg) {
    const int sw = (l15 & 7) << 4;
    #pragma unroll
    for (int j = 0; j < 2; ++j) {
        const char* rb = base + ((cq * 2 + j) * 16 + l15) * 128;
        bf[j][0] = *(const bf16x8*)(rb + ((lg * 16) ^ sw));
        bf[j][1] = *(const bf16x8*)(rb + ((64 + lg * 16) ^ sw));
    }
}
__device__ __forceinline__ void mfma16(f32x4 acc[8][4], const bf16x8 af[4][2], const bf16x8 bf[2][2],
                                       int mi0, int nj0) {
    __builtin_amdgcn_s_setprio(1);
    #pragma unroll
    for (int kk = 0; kk < 2; ++kk)
        #pragma unroll
        for (int i = 0; i < 4; ++i)
            #pragma unroll
            for (int j = 0; j < 2; ++j)
                acc[mi0 + i][nj0 + j] =
                    __builtin_amdgcn_mfma_f32_16x16x32_bf16(af[i][kk], bf[j][kk], acc[mi0 + i][nj0 + j], 0, 0, 0);
    __builtin_amdgcn_s_setprio(0);
}
__device__ __forceinline__ void stage2(const unsigned short* g, char* dst, int K, int r32, int kn) {
    gl16(g + (size_t)r32 * K + kn, dst);
    gl16(g + (size_t)(r32 + 8) * K + kn, dst + 1024);
}

template<bool OUT_BF16>
__global__ __launch_bounds__(512, 2)
void gemm256(const unsigned short* __restrict__ A,   // [M][K] bf16
             const unsigned short* __restrict__ Bt,  // [N][K] bf16
             void* __restrict__ Cp, int N, int K)
{
    extern __shared__ char lds[];
    const int tid = threadIdx.x;
    const int l   = tid & 63;
    const int l15 = l & 15, lg = l >> 4;
    const int wid = tid >> 6;
    const int wr  = wid >> 2;
    const int wc  = wid & 3;

    const int nwg = gridDim.x;
    const int bid = blockIdx.x;
    const int wgid = (bid & 7) * (nwg >> 3) + (bid >> 3);
    const int ntx = N >> 8;
    const int bx = wgid % ntx, by = wgid / ntx;
    const int m0 = by * 256, n0 = bx * 256;

    char* const Abase = lds + wr * 16384;
    char* const Bbase = lds + 32768 + (wc >> 1) * 16384 + (wc & 1) * 8192;

    const int l8 = l >> 3, l7 = l & 7;
    const int swslot = (l7 ^ l8) << 3;

    const unsigned short* Ag = A  + (size_t)(m0 + wr * 128 + wc * 16 + l8) * K + swslot;
    const unsigned short* Bg = Bt + (size_t)(n0 + wc * 64 + wr * 16 + l8) * K + swslot;
    char* const Adst = Abase + (wc * 16) * 128 + l * 16;
    char* const Bdst = Bbase + (wr * 16) * 128 + l * 16;

    f32x4 acc[8][4] = {};
    bf16x8 af[4][2], bf[2][2];

    stage2(Ag, Adst, K, 0, 0);
    stage2(Bg, Bdst, K, 0, 0);
    stage2(Ag, Adst + 64 * 128, K, 64, 0);
    stage2(Bg, Bdst + 32 * 128, K, 32, 0);
    VMCNT(0);
    BAR();

    const int NT = K >> 6;
    for (int t = 0; t < NT; ++t) {
        const int cb = (t & 1) * 65536, nb = cb ^ 65536;
        const int kn = (t + 1) << 6;
        const bool hn = (t + 1) < NT;
        lda4(af, Abase + cb, 0, l15, lg);
        ldb2(bf, Bbase + cb, 0, l15, lg);
        if (hn) stage2(Ag, Adst + nb, K, 0, kn);
        BAR();
        mfma16(acc, af, bf, 0, 0);
        VMCNT(4); LGKM0();
        BAR();
        lda4(af, Abase + cb, 1, l15, lg);
        if (hn) stage2(Bg, Bdst + nb, K, 0, kn);
        BAR();
        mfma16(acc, af, bf, 4, 0);
        VMCNT(4); LGKM0();
        BAR();
        ldb2(bf, Bbase + cb, 1, l15, lg);
        if (hn) stage2(Ag, Adst + nb + 64 * 128, K, 64, kn);
        BAR();
        mfma16(acc, af, bf, 4, 2);
        LGKM0();
        BAR();
        lda4(af, Abase + cb, 0, l15, lg);
        if (hn) stage2(Bg, Bdst + nb + 32 * 128, K, 32, kn);
        BAR();
        mfma16(acc, af, bf, 0, 2);
        VMCNT(4); LGKM0();
        BAR();
    }

    const int crow = m0 + wr * 128 + lg * 4;
    const int ccol = n0 + wc * 64 + l15;
    #pragma unroll
    for (int mi = 0; mi < 8; ++mi) {
        #pragma unroll
        for (int nj = 0; nj < 4; ++nj) {
            #pragma unroll
            for (int rr = 0; rr < 4; ++rr) {
                int row = crow + mi * 16 + rr;
                int col = ccol + nj * 16;
                float v = acc[mi][nj][rr];
                if (OUT_BF16) ((unsigned short*)Cp)[(size_t)row * N + col] = f2bf(v);
                else          ((float*)Cp)[(size_t)row * N + col] = v;
            }
        }
    }
}

// ---------------- per-head LayerNorm + RoPE, in place on combined QKV bf16 [S][12288] ----------------
__global__ __launch_bounds__(256)
void ln_rope(unsigned short* __restrict__ QKV,
             const float* __restrict__ qg, const float* __restrict__ qb,
             const float* __restrict__ kg, const float* __restrict__ kb,
             const int* __restrict__ pos)
{
    const int tid = threadIdx.x;
    const int l = tid & 63;
    const int w = tid >> 6;
    const int rid = blockIdx.x * 4 + w;
    const int s = rid >> 6;
    const int hh = rid & 63;
    const int which = hh >> 5;
    const int h = hh & 31;
    unsigned short* p = QKV + (size_t)s * QKV_N + which * HID + h * HD;
    const float* gamma = which ? kg : qg;
    const float* beta  = which ? kb : qb;

    float lo = bf2f(p[l]);
    float hi = bf2f(p[l + 64]);
    float sum = lo + hi;
    #pragma unroll
    for (int off = 32; off >= 1; off >>= 1) sum += __shfl_xor(sum, off, 64);
    float mu = sum * (1.0f / 128.0f);
    float dlo = lo - mu, dhi = hi - mu;
    float vs = dlo * dlo + dhi * dhi;
    #pragma unroll
    for (int off = 32; off >= 1; off >>= 1) vs += __shfl_xor(vs, off, 64);
    float rstd = rsqrtf(vs * (1.0f / 128.0f) + 1e-5f);
    float xlo = dlo * rstd * gamma[l] + beta[l];
    float xhi = dhi * rstd * gamma[l + 64] + beta[l + 64];

    float fpos = (float)pos[s];
    float invf = exp2f(-13.287712379549449f * (float)l * (1.0f / 64.0f));
    float ang = fpos * invf;
    float sn, cs;
    sincosf(ang, &sn, &cs);
    p[l]      = f2bf(xlo * cs - xhi * sn);
    p[l + 64] = f2bf(xhi * cs + xlo * sn);
}

// ---------------- causal flash attention, bf16 MFMA, KVB=64, V^T direct-global ----------------
#define KVB 64

__global__ __launch_bounds__(256)
void attn_fwd(const unsigned short* __restrict__ QKV,   // [S][12288]
              const unsigned short* __restrict__ Vtg,   // [4096][S]  (c = h*128+d major)
              unsigned short* __restrict__ O)           // [S][4096]
{
    __shared__ unsigned short Ks[2][KVB * HD];  // XOR-swizzled rows (256B), double-buffered
    __shared__ unsigned short Ps[4][16 * 72];   // per-wave P tile, stride 72

    const int tid = threadIdx.x;
    const int l = tid & 63;
    const int w = tid >> 6;
    const int l15 = l & 15, lg = l >> 4;
    const int h = blockIdx.y;
    const int qb = gridDim.x - 1 - blockIdx.x;   // longest blocks launch first
    const int q0 = qb * 64;
    const int qw = q0 + w * 16;

    const unsigned short* Qp = QKV + h * HD;
    const unsigned short* Kp = QKV + HID + h * HD;
    const unsigned short* Vp = Vtg + (size_t)h * HD * S_LEN;

    bf16x8 qf[4];
    #pragma unroll
    for (int d = 0; d < 4; ++d)
        qf[d] = *(const bf16x8*)&Qp[(size_t)(qw + l15) * QKV_N + d * 32 + lg * 8];

    f32x4 o_acc[8] = {};
    float mrow[4], lrow[4];
    #pragma unroll
    for (int r = 0; r < 4; ++r) { mrow[r] = -1e30f; lrow[r] = 0.0f; }

    const float scale = 0.08838834764831845f;

    // K staging map: row = tid>>2 (0..63), 4x16B at (tid&3)*64
    const int srow = tid >> 2;
    const int scb = (tid & 3) * 64;
    const int ssw = (srow & 7) << 4;
    const char* ksrc = (const char*)&Kp[(size_t)srow * QKV_N] + scb;
    const size_t kstep = (size_t)KVB * QKV_N * 2;

    bf16x8 kr[4];
    // prologue: stage tile 0 into buf 0
    #pragma unroll
    for (int j = 0; j < 4; ++j) kr[j] = *(const bf16x8*)(ksrc + j * 16);
    #pragma unroll
    for (int j = 0; j < 4; ++j)
        *(bf16x8*)((char*)Ks[0] + srow * 256 + ((scb + j * 16) ^ ssw)) = kr[j];
    ksrc += kstep;
    __syncthreads();

    const int nt = q0 / KVB + 1;
    for (int t = 0; t < nt; ++t) {
        const int kv0 = t * KVB;
        const int cur = t & 1;
        const bool hn = (t + 1) < nt;
        // async: issue next K tile loads to regs
        if (hn) {
            #pragma unroll
            for (int j = 0; j < 4; ++j) kr[j] = *(const bf16x8*)(ksrc + j * 16);
            ksrc += kstep;
        }
        // S = Q K^T
        f32x4 sc[4] = {};
        #pragma unroll
        for (int kvf = 0; kvf < 4; ++kvf) {
            int r = kvf * 16 + l15;
            int sw = (r & 7) << 4;
            #pragma unroll
            for (int d = 0; d < 4; ++d) {
                bf16x8 kf = *(const bf16x8*)((const char*)Ks[cur] + r * 256 + ((d * 64 + lg * 16) ^ sw));
                sc[kvf] = __builtin_amdgcn_mfma_f32_16x16x32_bf16(qf[d], kf, sc[kvf], 0, 0, 0);
            }
        }
        // online softmax (defer-max, THR=8)
        #pragma unroll
        for (int r = 0; r < 4; ++r) {
            int qg = qw + lg * 4 + r;
            float s0 = (kv0 + l15      <= qg) ? sc[0][r] * scale : -1e30f;
            float s1 = (kv0 + 16 + l15 <= qg) ? sc[1][r] * scale : -1e30f;
            float s2 = (kv0 + 32 + l15 <= qg) ? sc[2][r] * scale : -1e30f;
            float s3 = (kv0 + 48 + l15 <= qg) ? sc[3][r] * scale : -1e30f;
            float mx = fmaxf(fmaxf(s0, s1), fmaxf(s2, s3));
            #pragma unroll
            for (int off = 8; off >= 1; off >>= 1) mx = fmaxf(mx, __shfl_xor(mx, off, 64));
            float mn = mrow[r];
            if (!__all(mx <= mn + 8.0f)) {
                mn = fmaxf(mn, mx);
                float corr = __expf(mrow[r] - mn);
                lrow[r] *= corr;
                #pragma unroll
                for (int df = 0; df < 8; ++df) o_acc[df][r] *= corr;
                mrow[r] = mn;
            }
            float p0 = __expf(s0 - mn);
            float p1 = __expf(s1 - mn);
            float p2 = __expf(s2 - mn);
            float p3 = __expf(s3 - mn);
            float rs = (p0 + p1) + (p2 + p3);
            #pragma unroll
            for (int off = 8; off >= 1; off >>= 1) rs += __shfl_xor(rs, off, 64);
            lrow[r] += rs;
            int ql = lg * 4 + r;
            Ps[w][ql * 72 + l15]      = f2bf(p0);
            Ps[w][ql * 72 + 16 + l15] = f2bf(p1);
            Ps[w][ql * 72 + 32 + l15] = f2bf(p2);
            Ps[w][ql * 72 + 48 + l15] = f2bf(p3);
        }
        // O += P V  (V^T rows direct from global, kv-contiguous)
        bf16x8 pa0 = *(const bf16x8*)&Ps[w][l15 * 72 + lg * 8];
        bf16x8 pa1 = *(const bf16x8*)&Ps[w][l15 * 72 + 32 + lg * 8];
        const unsigned short* vrow = &Vp[(size_t)l15 * S_LEN + kv0 + lg * 8];
        #pragma unroll
        for (int df = 0; df < 8; ++df) {
            bf16x8 v0 = *(const bf16x8*)(vrow + (size_t)df * 16 * S_LEN);
            bf16x8 v1 = *(const bf16x8*)(vrow + (size_t)df * 16 * S_LEN + 32);
            o_acc[df] = __builtin_amdgcn_mfma_f32_16x16x32_bf16(pa0, v0, o_acc[df], 0, 0, 0);
            o_acc[df] = __builtin_amdgcn_mfma_f32_16x16x32_bf16(pa1, v1, o_acc[df], 0, 0, 0);
        }
        // write next K tile to alternate buffer
        if (hn) {
            #pragma unroll
            for (int j = 0; j < 4; ++j)
                *(bf16x8*)((char*)Ks[cur ^ 1] + srow * 256 + ((scb + j * 16) ^ ssw)) = kr[j];
        }
        __syncthreads();
    }

    #pragma unroll
    for (int df = 0; df < 8; ++df) {
        float inv[4];
        #pragma unroll
        for (int r = 0; r < 4; ++r) inv[r] = 1.0f / lrow[r];
        #pragma unroll
        for (int r = 0; r < 4; ++r) {
            int q = qw + lg * 4 + r;
            int d = h * HD + df * 16 + l15;
            O[(size_t)q * HID + d] = f2bf(o_acc[df][r] * inv[r]);
        }
    }
}

extern "C" void kernel_launch(void* const* d_in, const int* in_sizes, int n_in,
                              void* d_out, int out_size, void* d_ws, size_t ws_size,
                              hipStream_t stream)
{
    (void)in_sizes; (void)n_in; (void)out_size; (void)ws_size;
    const float* X    = (const float*)d_in[0];
    const int*   pos  = (const int*)d_in[1];
    const float* Wq   = (const float*)d_in[2];
    const float* Wk   = (const float*)d_in[3];
    const float* Wv   = (const float*)d_in[4];
    const float* Wo   = (const float*)d_in[5];
    const float* qn_w = (const float*)d_in[6];
    const float* qn_b = (const float*)d_in[7];
    const float* kn_w = (const float*)d_in[8];
    const float* kn_b = (const float*)d_in[9];
    float* out = (float*)d_out;

    unsigned short* Xb    = (unsigned short*)d_ws;
    unsigned short* QKVb  = (unsigned short*)((char*)d_ws + 16777216);
    unsigned short* Wt    = (unsigned short*)((char*)d_ws + 67108864);
    unsigned short* Vtg   = (unsigned short*)((char*)d_ws + 134217728);  // 3rd weight slot (dead after QKV GEMM)
    unsigned short* Ab    = Xb;

    {
        auto k1 = gemm256<true>;
        auto k2 = gemm256<false>;
        (void)hipFuncSetAttribute((const void*)k1, hipFuncAttributeMaxDynamicSharedMemorySize, 131072);
        (void)hipFuncSetAttribute((const void*)k2, hipFuncAttributeMaxDynamicSharedMemorySize, 131072);
    }

    dim3 blk(256);

    cvt_f32_bf16<<<dim3((S_LEN * HID / 8 + 255) / 256), blk, 0, stream>>>(X, Xb, S_LEN * HID / 8);

    dim3 tgrid(HID / 64, HID / 64);
    cvt_w_t<<<tgrid, blk, 0, stream>>>(Wq, Wt,                         HID, HID);
    cvt_w_t<<<tgrid, blk, 0, stream>>>(Wk, Wt + (size_t)HID * HID,     HID, HID);
    cvt_w_t<<<tgrid, blk, 0, stream>>>(Wv, Wt + (size_t)2 * HID * HID, HID, HID);

    gemm256<true><<<dim3((S_LEN / 256) * (QKV_N / 256)), dim3(512), 131072, stream>>>(Xb, Wt, QKVb, QKV_N, HID);

    // V^T materialization (V slab is not LN/RoPE'd) + LN/RoPE on Q,K
    v_transpose<<<dim3(S_LEN / 64, HID / 64), blk, 0, stream>>>(QKVb, Vtg);
    ln_rope<<<dim3(S_LEN * 64 / 4), blk, 0, stream>>>(QKVb, qn_w, qn_b, kn_w, kn_b, pos);

    attn_fwd<<<dim3(S_LEN / 64, NH), blk, 0, stream>>>(QKVb, Vtg, Ab);

    cvt_w_t<<<tgrid, blk, 0, stream>>>(Wo, Wt, HID, HID);

    gemm256<false><<<dim3((S_LEN / 256) * (HID / 256)), dim3(512), 131072, stream>>>(Ab, Wt, out, HID, HID);
}

// Round 5
// 648.036 us; speedup vs baseline: 1.2140x; 1.2140x over previous
//
#include <hip/hip_runtime.h>

#define S_LEN 2048
#define HID 4096
#define NH 32
#define HD 128
#define QKV_N 12288   // 3*HID

typedef __attribute__((ext_vector_type(8))) short bf16x8;
typedef __attribute__((ext_vector_type(4))) float f32x4;

__device__ __forceinline__ unsigned short f2bf(float f) {
    unsigned int u = __float_as_uint(f);
    u += 0x7FFF + ((u >> 16) & 1);
    return (unsigned short)(u >> 16);
}
__device__ __forceinline__ float bf2f(unsigned short h) {
    return __uint_as_float(((unsigned int)h) << 16);
}

typedef __attribute__((address_space(1))) const void gconst_void;
typedef __attribute__((address_space(3))) void lds_void;
__device__ __forceinline__ void gl16(const void* g, void* l) {
    __builtin_amdgcn_global_load_lds((gconst_void*)g, (lds_void*)l, 16, 0, 0);
}

#define VMCNT(n) asm volatile("s_waitcnt vmcnt(" #n ")" ::: "memory")
#define LGKM0()  asm volatile("s_waitcnt lgkmcnt(0)" ::: "memory")
#define BAR()    do { asm volatile("" ::: "memory"); __builtin_amdgcn_s_barrier(); asm volatile("" ::: "memory"); } while (0)

// ---------------- fp32 -> bf16 linear convert ----------------
__global__ __launch_bounds__(256)
void cvt_f32_bf16(const float* __restrict__ in, unsigned short* __restrict__ out, int n8)
{
    int i = blockIdx.x * 256 + threadIdx.x;
    if (i >= n8) return;
    const float4* p = (const float4*)in + (size_t)i * 2;
    float4 a = p[0], b = p[1];
    bf16x8 o;
    o[0] = (short)f2bf(a.x); o[1] = (short)f2bf(a.y); o[2] = (short)f2bf(a.z); o[3] = (short)f2bf(a.w);
    o[4] = (short)f2bf(b.x); o[5] = (short)f2bf(b.y); o[6] = (short)f2bf(b.z); o[7] = (short)f2bf(b.w);
    *((bf16x8*)out + i) = o;
}

// ---------------- fp32 [K][N] -> bf16 [N][K] transpose-convert ----------------
__global__ __launch_bounds__(256)
void cvt_w_t(const float* __restrict__ W, unsigned short* __restrict__ Wt, int N, int K)
{
    __shared__ unsigned short t[64][72];
    const int tid = threadIdx.x;
    const int n0 = blockIdx.x * 64, k0 = blockIdx.y * 64;
    const int c4 = (tid & 15) * 4;
    const int r  = tid >> 4;
    #pragma unroll
    for (int p = 0; p < 4; ++p) {
        float4 v = *(const float4*)&W[(size_t)(k0 + r + p * 16) * N + n0 + c4];
        ushort4 o;
        o.x = f2bf(v.x); o.y = f2bf(v.y); o.z = f2bf(v.z); o.w = f2bf(v.w);
        *(ushort4*)&t[r + p * 16][c4] = o;
    }
    __syncthreads();
    const int n = tid >> 2;
    const int kq = (tid & 3) * 16;
    unsigned short* dst = &Wt[(size_t)(n0 + n) * K + k0 + kq];
    bf16x8 v0, v1;
    #pragma unroll
    for (int j = 0; j < 8; ++j) v0[j] = (short)t[kq + j][n];
    #pragma unroll
    for (int j = 0; j < 8; ++j) v1[j] = (short)t[kq + 8 + j][n];
    *(bf16x8*)dst = v0;
    *(bf16x8*)(dst + 8) = v1;
}

// ---------------- bf16 V slab [s][c] -> Vtg [c][s] transpose ----------------
__global__ __launch_bounds__(256)
void v_transpose(const unsigned short* __restrict__ QKV, unsigned short* __restrict__ Vtg)
{
    __shared__ unsigned short t[64][72];
    const int tid = threadIdx.x;
    const int s0 = blockIdx.x * 64;
    const int c0 = blockIdx.y * 64;
    #pragma unroll
    for (int i = 0; i < 2; ++i) {
        int idx = i * 256 + tid;
        int r = idx >> 3, c8 = (idx & 7) * 8;
        *(bf16x8*)&t[r][c8] = *(const bf16x8*)&QKV[(size_t)(s0 + r) * QKV_N + 2 * HID + c0 + c8];
    }
    __syncthreads();
    #pragma unroll
    for (int i = 0; i < 2; ++i) {
        int idx = i * 256 + tid;
        int oc = idx >> 3, os8 = (idx & 7) * 8;
        bf16x8 v;
        #pragma unroll
        for (int j = 0; j < 8; ++j) v[j] = (short)t[os8 + j][oc];
        *(bf16x8*)&Vtg[(size_t)(c0 + oc) * S_LEN + s0 + os8] = v;
    }
}

// ---------------- 256x256 8-phase GEMM: C = A[M,K] * Bt[N,K]^T ----------------
__device__ __forceinline__ void lda4(bf16x8 af[4][2], const char* base, int rq, int l15, int lg) {
    const int sw = (l15 & 7) << 4;
    #pragma unroll
    for (int i = 0; i < 4; ++i) {
        const char* rb = base + ((rq * 4 + i) * 16 + l15) * 128;
        af[i][0] = *(const bf16x8*)(rb + ((lg * 16) ^ sw));
        af[i][1] = *(const bf16x8*)(rb + ((64 + lg * 16) ^ sw));
    }
}
__device__ __forceinline__ void ldb2(bf16x8 bf[2][2], const char* base, int cq, int l15, int lg) {
    const int sw = (l15 & 7) << 4;
    #pragma unroll
    for (int j = 0; j < 2; ++j) {
        const char* rb = base + ((cq * 2 + j) * 16 + l15) * 128;
        bf[j][0] = *(const bf16x8*)(rb + ((lg * 16) ^ sw));
        bf[j][1] = *(const bf16x8*)(rb + ((64 + lg * 16) ^ sw));
    }
}
__device__ __forceinline__ void mfma16(f32x4 acc[8][4], const bf16x8 af[4][2], const bf16x8 bf[2][2],
                                       int mi0, int nj0) {
    __builtin_amdgcn_s_setprio(1);
    #pragma unroll
    for (int kk = 0; kk < 2; ++kk)
        #pragma unroll
        for (int i = 0; i < 4; ++i)
            #pragma unroll
            for (int j = 0; j < 2; ++j)
                acc[mi0 + i][nj0 + j] =
                    __builtin_amdgcn_mfma_f32_16x16x32_bf16(af[i][kk], bf[j][kk], acc[mi0 + i][nj0 + j], 0, 0, 0);
    __builtin_amdgcn_s_setprio(0);
}
__device__ __forceinline__ void stage2(const unsigned short* g, char* dst, int K, int r32, int kn) {
    gl16(g + (size_t)r32 * K + kn, dst);
    gl16(g + (size_t)(r32 + 8) * K + kn, dst + 1024);
}

template<bool OUT_BF16>
__global__ __launch_bounds__(512, 2)
void gemm256(const unsigned short* __restrict__ A,   // [M][K] bf16
             const unsigned short* __restrict__ Bt,  // [N][K] bf16
             void* __restrict__ Cp, int N, int K)
{
    extern __shared__ char lds[];
    const int tid = threadIdx.x;
    const int l   = tid & 63;
    const int l15 = l & 15, lg = l >> 4;
    const int wid = tid >> 6;
    const int wr  = wid >> 2;
    const int wc  = wid & 3;

    const int nwg = gridDim.x;
    const int bid = blockIdx.x;
    const int wgid = (bid & 7) * (nwg >> 3) + (bid >> 3);
    const int ntx = N >> 8;
    const int bx = wgid % ntx, by = wgid / ntx;
    const int m0 = by * 256, n0 = bx * 256;

    char* const Abase = lds + wr * 16384;
    char* const Bbase = lds + 32768 + (wc >> 1) * 16384 + (wc & 1) * 8192;

    const int l8 = l >> 3, l7 = l & 7;
    const int swslot = (l7 ^ l8) << 3;

    const unsigned short* Ag = A  + (size_t)(m0 + wr * 128 + wc * 16 + l8) * K + swslot;
    const unsigned short* Bg = Bt + (size_t)(n0 + wc * 64 + wr * 16 + l8) * K + swslot;
    char* const Adst = Abase + (wc * 16) * 128 + l * 16;
    char* const Bdst = Bbase + (wr * 16) * 128 + l * 16;

    f32x4 acc[8][4] = {};
    bf16x8 af[4][2], bf[2][2];

    stage2(Ag, Adst, K, 0, 0);
    stage2(Bg, Bdst, K, 0, 0);
    stage2(Ag, Adst + 64 * 128, K, 64, 0);
    stage2(Bg, Bdst + 32 * 128, K, 32, 0);
    VMCNT(0);
    BAR();

    const int NT = K >> 6;
    for (int t = 0; t < NT; ++t) {
        const int cb = (t & 1) * 65536, nb = cb ^ 65536;
        const int kn = (t + 1) << 6;
        const bool hn = (t + 1) < NT;
        lda4(af, Abase + cb, 0, l15, lg);
        ldb2(bf, Bbase + cb, 0, l15, lg);
        if (hn) stage2(Ag, Adst + nb, K, 0, kn);
        BAR();
        mfma16(acc, af, bf, 0, 0);
        VMCNT(4); LGKM0();
        BAR();
        lda4(af, Abase + cb, 1, l15, lg);
        if (hn) stage2(Bg, Bdst + nb, K, 0, kn);
        BAR();
        mfma16(acc, af, bf, 4, 0);
        VMCNT(4); LGKM0();
        BAR();
        ldb2(bf, Bbase + cb, 1, l15, lg);
        if (hn) stage2(Ag, Adst + nb + 64 * 128, K, 64, kn);
        BAR();
        mfma16(acc, af, bf, 4, 2);
        LGKM0();
        BAR();
        lda4(af, Abase + cb, 0, l15, lg);
        if (hn) stage2(Bg, Bdst + nb + 32 * 128, K, 32, kn);
        BAR();
        mfma16(acc, af, bf, 0, 2);
        VMCNT(4); LGKM0();
        BAR();
    }

    const int crow = m0 + wr * 128 + lg * 4;
    const int ccol = n0 + wc * 64 + l15;
    #pragma unroll
    for (int mi = 0; mi < 8; ++mi) {
        #pragma unroll
        for (int nj = 0; nj < 4; ++nj) {
            #pragma unroll
            for (int rr = 0; rr < 4; ++rr) {
                int row = crow + mi * 16 + rr;
                int col = ccol + nj * 16;
                float v = acc[mi][nj][rr];
                if (OUT_BF16) ((unsigned short*)Cp)[(size_t)row * N + col] = f2bf(v);
                else          ((float*)Cp)[(size_t)row * N + col] = v;
            }
        }
    }
}

// ---------------- per-head LayerNorm + RoPE, in place on combined QKV bf16 [S][12288] ----------------
__global__ __launch_bounds__(256)
void ln_rope(unsigned short* __restrict__ QKV,
             const float* __restrict__ qg, const float* __restrict__ qb,
             const float* __restrict__ kg, const float* __restrict__ kb,
             const int* __restrict__ pos)
{
    const int tid = threadIdx.x;
    const int l = tid & 63;
    const int w = tid >> 6;
    const int rid = blockIdx.x * 4 + w;
    const int s = rid >> 6;
    const int hh = rid & 63;
    const int which = hh >> 5;
    const int h = hh & 31;
    unsigned short* p = QKV + (size_t)s * QKV_N + which * HID + h * HD;
    const float* gamma = which ? kg : qg;
    const float* beta  = which ? kb : qb;

    float lo = bf2f(p[l]);
    float hi = bf2f(p[l + 64]);
    float sum = lo + hi;
    #pragma unroll
    for (int off = 32; off >= 1; off >>= 1) sum += __shfl_xor(sum, off, 64);
    float mu = sum * (1.0f / 128.0f);
    float dlo = lo - mu, dhi = hi - mu;
    float vs = dlo * dlo + dhi * dhi;
    #pragma unroll
    for (int off = 32; off >= 1; off >>= 1) vs += __shfl_xor(vs, off, 64);
    float rstd = rsqrtf(vs * (1.0f / 128.0f) + 1e-5f);
    float xlo = dlo * rstd * gamma[l] + beta[l];
    float xhi = dhi * rstd * gamma[l + 64] + beta[l + 64];

    float fpos = (float)pos[s];
    float invf = exp2f(-13.287712379549449f * (float)l * (1.0f / 64.0f));
    float ang = fpos * invf;
    float sn, cs;
    sincosf(ang, &sn, &cs);
    p[l]      = f2bf(xlo * cs - xhi * sn);
    p[l + 64] = f2bf(xhi * cs + xlo * sn);
}

// ---------------- causal flash attention: KVB=64, K & V^T LDS-dbuf via global_load_lds ----------------
#define KVB 64

__global__ __launch_bounds__(256)
void attn_fwd(const unsigned short* __restrict__ QKV,   // [S][12288]
              const unsigned short* __restrict__ Vtg,   // [4096][S]
              unsigned short* __restrict__ O)           // [S][4096]
{
    __shared__ unsigned short Ks[2][KVB * HD];  // 16KB each; row 256B, slot^(r&7) swizzle
    __shared__ unsigned short Vs[2][HD * KVB];  // 16KB each; [d][kv] row 128B, slot^(d&7)
    __shared__ unsigned short Ps[4][16 * 72];

    const int tid = threadIdx.x;
    const int l = tid & 63;
    const int w = tid >> 6;
    const int l15 = l & 15, lg = l >> 4;
    const int h = blockIdx.y;
    const int qb = gridDim.x - 1 - blockIdx.x;   // longest blocks first
    const int q0 = qb * 64;
    const int qw = q0 + w * 16;

    const unsigned short* Qp = QKV + h * HD;
    const unsigned short* Kp = QKV + HID + h * HD;
    const unsigned short* Vp = Vtg + (size_t)h * HD * S_LEN;

    bf16x8 qf[4];
    #pragma unroll
    for (int d = 0; d < 4; ++d)
        qf[d] = *(const bf16x8*)&Qp[(size_t)(qw + l15) * QKV_N + d * 32 + lg * 8];

    f32x4 o_acc[8] = {};
    float mrow[4], lrow[4];
    #pragma unroll
    for (int r = 0; r < 4; ++r) { mrow[r] = -1e30f; lrow[r] = 0.0f; }

    const float scale = 0.08838834764831845f;

    // staging address maps (pre-swizzled global sources, linear LDS dests)
    // K: chunk ci=i*256+tid -> row r=i*16+(tid>>4), slot_l=tid&15; slot_g=(sl&8)|((sl^(r&7))&7)
    const int ksl = tid & 15;
    const int kr7 = (tid >> 4) & 7;
    const int ksg = (ksl & 8) | ((ksl ^ kr7) & 7);
    const unsigned short* Kg = Kp + (size_t)(tid >> 4) * QKV_N + ksg * 8;
    // V: chunk ci=i*256+tid -> row d=i*32+(tid>>3), slot_l=tid&7; slot_g=sl^(d&7)
    const int vsg = (tid & 7) ^ ((tid >> 3) & 7);
    const unsigned short* Vg = Vp + (size_t)(tid >> 3) * S_LEN + vsg * 8;

#define STAGE(buf, kv0s) do {                                                          \
    _Pragma("unroll")                                                                  \
    for (int i_ = 0; i_ < 4; ++i_)                                                     \
        gl16(Kg + (size_t)((kv0s) + i_ * 16) * QKV_N,                                  \
             (char*)Ks[buf] + (i_ * 256 + tid) * 16);                                  \
    _Pragma("unroll")                                                                  \
    for (int i_ = 0; i_ < 4; ++i_)                                                     \
        gl16(Vg + (size_t)i_ * 32 * S_LEN + (kv0s),                                    \
             (char*)Vs[buf] + (i_ * 256 + tid) * 16);                                  \
} while (0)

    STAGE(0, 0);
    VMCNT(0);
    __syncthreads();

    const int nt = q0 / KVB + 1;
    for (int t = 0; t < nt; ++t) {
        const int kv0 = t * KVB;
        const int cur = t & 1;
        const bool hn = (t + 1) < nt;
        if (hn) STAGE(cur ^ 1, kv0 + KVB);

        // S = Q K^T from Ks[cur]
        f32x4 sc[4] = {};
        #pragma unroll
        for (int kvf = 0; kvf < 4; ++kvf) {
            int r = kvf * 16 + l15;
            int sw = (r & 7) << 4;
            #pragma unroll
            for (int d = 0; d < 4; ++d) {
                bf16x8 kf = *(const bf16x8*)((const char*)Ks[cur] + r * 256 + ((d * 64 + lg * 16) ^ sw));
                sc[kvf] = __builtin_amdgcn_mfma_f32_16x16x32_bf16(qf[d], kf, sc[kvf], 0, 0, 0);
            }
        }

        // online softmax (defer-max THR=8); wave-uniform full-tile fast path
        const bool full = (kv0 + KVB <= qw);
        #pragma unroll
        for (int r = 0; r < 4; ++r) {
            int qg = qw + lg * 4 + r;
            float s0, s1, s2, s3;
            if (full) {
                s0 = sc[0][r] * scale; s1 = sc[1][r] * scale;
                s2 = sc[2][r] * scale; s3 = sc[3][r] * scale;
            } else {
                s0 = (kv0 + l15      <= qg) ? sc[0][r] * scale : -1e30f;
                s1 = (kv0 + 16 + l15 <= qg) ? sc[1][r] * scale : -1e30f;
                s2 = (kv0 + 32 + l15 <= qg) ? sc[2][r] * scale : -1e30f;
                s3 = (kv0 + 48 + l15 <= qg) ? sc[3][r] * scale : -1e30f;
            }
            float mx = fmaxf(fmaxf(s0, s1), fmaxf(s2, s3));
            #pragma unroll
            for (int off = 8; off >= 1; off >>= 1) mx = fmaxf(mx, __shfl_xor(mx, off, 64));
            float mn = mrow[r];
            if (!__all(mx <= mn + 8.0f)) {
                mn = fmaxf(mn, mx);
                float corr = __expf(mrow[r] - mn);
                lrow[r] *= corr;
                #pragma unroll
                for (int df = 0; df < 8; ++df) o_acc[df][r] *= corr;
                mrow[r] = mn;
            }
            float p0 = __expf(s0 - mn);
            float p1 = __expf(s1 - mn);
            float p2 = __expf(s2 - mn);
            float p3 = __expf(s3 - mn);
            float rs = (p0 + p1) + (p2 + p3);
            #pragma unroll
            for (int off = 8; off >= 1; off >>= 1) rs += __shfl_xor(rs, off, 64);
            lrow[r] += rs;
            int ql = lg * 4 + r;
            Ps[w][ql * 72 + l15]      = f2bf(p0);
            Ps[w][ql * 72 + 16 + l15] = f2bf(p1);
            Ps[w][ql * 72 + 32 + l15] = f2bf(p2);
            Ps[w][ql * 72 + 48 + l15] = f2bf(p3);
        }

        // O += P V from Vs[cur]
        bf16x8 pa0 = *(const bf16x8*)&Ps[w][l15 * 72 + lg * 8];
        bf16x8 pa1 = *(const bf16x8*)&Ps[w][l15 * 72 + 32 + lg * 8];
        #pragma unroll
        for (int df = 0; df < 8; ++df) {
            int d = df * 16 + l15;
            int sw = (d & 7) << 4;
            const char* vrow = (const char*)Vs[cur] + d * 128;
            bf16x8 v0 = *(const bf16x8*)(vrow + ((lg * 16) ^ sw));
            bf16x8 v1 = *(const bf16x8*)(vrow + ((64 + lg * 16) ^ sw));
            o_acc[df] = __builtin_amdgcn_mfma_f32_16x16x32_bf16(pa0, v0, o_acc[df], 0, 0, 0);
            o_acc[df] = __builtin_amdgcn_mfma_f32_16x16x32_bf16(pa1, v1, o_acc[df], 0, 0, 0);
        }

        VMCNT(0);
        BAR();
    }
#undef STAGE

    #pragma unroll
    for (int df = 0; df < 8; ++df) {
        #pragma unroll
        for (int r = 0; r < 4; ++r) {
            int q = qw + lg * 4 + r;
            int d = h * HD + df * 16 + l15;
            O[(size_t)q * HID + d] = f2bf(o_acc[df][r] / lrow[r]);
        }
    }
}

extern "C" void kernel_launch(void* const* d_in, const int* in_sizes, int n_in,
                              void* d_out, int out_size, void* d_ws, size_t ws_size,
                              hipStream_t stream)
{
    (void)in_sizes; (void)n_in; (void)out_size; (void)ws_size;
    const float* X    = (const float*)d_in[0];
    const int*   pos  = (const int*)d_in[1];
    const float* Wq   = (const float*)d_in[2];
    const float* Wk   = (const float*)d_in[3];
    const float* Wv   = (const float*)d_in[4];
    const float* Wo   = (const float*)d_in[5];
    const float* qn_w = (const float*)d_in[6];
    const float* qn_b = (const float*)d_in[7];
    const float* kn_w = (const float*)d_in[8];
    const float* kn_b = (const float*)d_in[9];
    float* out = (float*)d_out;

    unsigned short* Xb    = (unsigned short*)d_ws;
    unsigned short* QKVb  = (unsigned short*)((char*)d_ws + 16777216);
    unsigned short* Wt    = (unsigned short*)((char*)d_ws + 67108864);
    unsigned short* Vtg   = (unsigned short*)((char*)d_ws + 134217728);
    unsigned short* Ab    = Xb;

    {
        auto k1 = gemm256<true>;
        auto k2 = gemm256<false>;
        (void)hipFuncSetAttribute((const void*)k1, hipFuncAttributeMaxDynamicSharedMemorySize, 131072);
        (void)hipFuncSetAttribute((const void*)k2, hipFuncAttributeMaxDynamicSharedMemorySize, 131072);
    }

    dim3 blk(256);

    cvt_f32_bf16<<<dim3((S_LEN * HID / 8 + 255) / 256), blk, 0, stream>>>(X, Xb, S_LEN * HID / 8);

    dim3 tgrid(HID / 64, HID / 64);
    cvt_w_t<<<tgrid, blk, 0, stream>>>(Wq, Wt,                         HID, HID);
    cvt_w_t<<<tgrid, blk, 0, stream>>>(Wk, Wt + (size_t)HID * HID,     HID, HID);
    cvt_w_t<<<tgrid, blk, 0, stream>>>(Wv, Wt + (size_t)2 * HID * HID, HID, HID);

    gemm256<true><<<dim3((S_LEN / 256) * (QKV_N / 256)), dim3(512), 131072, stream>>>(Xb, Wt, QKVb, QKV_N, HID);

    v_transpose<<<dim3(S_LEN / 64, HID / 64), blk, 0, stream>>>(QKVb, Vtg);
    ln_rope<<<dim3(S_LEN * 64 / 4), blk, 0, stream>>>(QKVb, qn_w, qn_b, kn_w, kn_b, pos);

    attn_fwd<<<dim3(S_LEN / 64, NH), blk, 0, stream>>>(QKVb, Vtg, Ab);

    cvt_w_t<<<tgrid, blk, 0, stream>>>(Wo, Wt, HID, HID);

    gemm256<false><<<dim3((S_LEN / 256) * (HID / 256)), dim3(512), 131072, stream>>>(Ab, Wt, out, HID, HID);
}

// Round 6
// 632.983 us; speedup vs baseline: 1.2429x; 1.0238x over previous
//
#include <hip/hip_runtime.h>

#define S_LEN 2048
#define HID 4096
#define NH 32
#define HD 128
#define QKV_N 12288   // 3*HID

typedef __attribute__((ext_vector_type(8))) short bf16x8;
typedef __attribute__((ext_vector_type(4))) float f32x4;

__device__ __forceinline__ unsigned short f2bf(float f) {
    unsigned int u = __float_as_uint(f);
    u += 0x7FFF + ((u >> 16) & 1);
    return (unsigned short)(u >> 16);
}
__device__ __forceinline__ float bf2f(unsigned short h) {
    return __uint_as_float(((unsigned int)h) << 16);
}

typedef __attribute__((address_space(1))) const void gconst_void;
typedef __attribute__((address_space(3))) void lds_void;
__device__ __forceinline__ void gl16(const void* g, void* l) {
    __builtin_amdgcn_global_load_lds((gconst_void*)g, (lds_void*)l, 16, 0, 0);
}

#define VMCNT(n) asm volatile("s_waitcnt vmcnt(" #n ")" ::: "memory")
#define LGKM0()  asm volatile("s_waitcnt lgkmcnt(0)" ::: "memory")
#define BAR()    do { asm volatile("" ::: "memory"); __builtin_amdgcn_s_barrier(); asm volatile("" ::: "memory"); } while (0)

// ---------------- fp32 -> bf16 linear convert ----------------
__global__ __launch_bounds__(256)
void cvt_f32_bf16(const float* __restrict__ in, unsigned short* __restrict__ out, int n8)
{
    int i = blockIdx.x * 256 + threadIdx.x;
    if (i >= n8) return;
    const float4* p = (const float4*)in + (size_t)i * 2;
    float4 a = p[0], b = p[1];
    bf16x8 o;
    o[0] = (short)f2bf(a.x); o[1] = (short)f2bf(a.y); o[2] = (short)f2bf(a.z); o[3] = (short)f2bf(a.w);
    o[4] = (short)f2bf(b.x); o[5] = (short)f2bf(b.y); o[6] = (short)f2bf(b.z); o[7] = (short)f2bf(b.w);
    *((bf16x8*)out + i) = o;
}

// ---------------- fp32 [K][N] -> bf16 [N][K] transpose-convert (3 weights in one launch) ----------------
struct W3 { const float* w0; const float* w1; const float* w2; };

__global__ __launch_bounds__(256)
void cvt_w_t3(W3 ws3, unsigned short* __restrict__ Wt, int N, int K)
{
    __shared__ unsigned short t[64][72];
    const float* W = blockIdx.z == 0 ? ws3.w0 : (blockIdx.z == 1 ? ws3.w1 : ws3.w2);
    unsigned short* Wto = Wt + (size_t)blockIdx.z * N * K;
    const int tid = threadIdx.x;
    const int n0 = blockIdx.x * 64, k0 = blockIdx.y * 64;
    const int c4 = (tid & 15) * 4;
    const int r  = tid >> 4;
    #pragma unroll
    for (int p = 0; p < 4; ++p) {
        float4 v = *(const float4*)&W[(size_t)(k0 + r + p * 16) * N + n0 + c4];
        ushort4 o;
        o.x = f2bf(v.x); o.y = f2bf(v.y); o.z = f2bf(v.z); o.w = f2bf(v.w);
        *(ushort4*)&t[r + p * 16][c4] = o;
    }
    __syncthreads();
    const int n = tid >> 2;
    const int kq = (tid & 3) * 16;
    unsigned short* dst = &Wto[(size_t)(n0 + n) * K + k0 + kq];
    bf16x8 v0, v1;
    #pragma unroll
    for (int j = 0; j < 8; ++j) v0[j] = (short)t[kq + j][n];
    #pragma unroll
    for (int j = 0; j < 8; ++j) v1[j] = (short)t[kq + 8 + j][n];
    *(bf16x8*)dst = v0;
    *(bf16x8*)(dst + 8) = v1;
}

// ---------------- bf16 V slab [s][c] -> Vtg [c][s] transpose ----------------
__global__ __launch_bounds__(256)
void v_transpose(const unsigned short* __restrict__ QKV, unsigned short* __restrict__ Vtg)
{
    __shared__ unsigned short t[64][72];
    const int tid = threadIdx.x;
    const int s0 = blockIdx.x * 64;
    const int c0 = blockIdx.y * 64;
    #pragma unroll
    for (int i = 0; i < 2; ++i) {
        int idx = i * 256 + tid;
        int r = idx >> 3, c8 = (idx & 7) * 8;
        *(bf16x8*)&t[r][c8] = *(const bf16x8*)&QKV[(size_t)(s0 + r) * QKV_N + 2 * HID + c0 + c8];
    }
    __syncthreads();
    #pragma unroll
    for (int i = 0; i < 2; ++i) {
        int idx = i * 256 + tid;
        int oc = idx >> 3, os8 = (idx & 7) * 8;
        bf16x8 v;
        #pragma unroll
        for (int j = 0; j < 8; ++j) v[j] = (short)t[os8 + j][oc];
        *(bf16x8*)&Vtg[(size_t)(c0 + oc) * S_LEN + s0 + os8] = v;
    }
}

// ---------------- 256x256 8-phase GEMM: C = A[M,K] * Bt[N,K]^T ----------------
__device__ __forceinline__ void lda4(bf16x8 af[4][2], const char* base, int rq, int l15, int lg) {
    const int sw = (l15 & 7) << 4;
    #pragma unroll
    for (int i = 0; i < 4; ++i) {
        const char* rb = base + ((rq * 4 + i) * 16 + l15) * 128;
        af[i][0] = *(const bf16x8*)(rb + ((lg * 16) ^ sw));
        af[i][1] = *(const bf16x8*)(rb + ((64 + lg * 16) ^ sw));
    }
}
__device__ __forceinline__ void ldb2(bf16x8 bf[2][2], const char* base, int cq, int l15, int lg) {
    const int sw = (l15 & 7) << 4;
    #pragma unroll
    for (int j = 0; j < 2; ++j) {
        const char* rb = base + ((cq * 2 + j) * 16 + l15) * 128;
        bf[j][0] = *(const bf16x8*)(rb + ((lg * 16) ^ sw));
        bf[j][1] = *(const bf16x8*)(rb + ((64 + lg * 16) ^ sw));
    }
}
__device__ __forceinline__ void mfma16(f32x4 acc[8][4], const bf16x8 af[4][2], const bf16x8 bf[2][2],
                                       int mi0, int nj0) {
    __builtin_amdgcn_s_setprio(1);
    #pragma unroll
    for (int kk = 0; kk < 2; ++kk)
        #pragma unroll
        for (int i = 0; i < 4; ++i)
            #pragma unroll
            for (int j = 0; j < 2; ++j)
                acc[mi0 + i][nj0 + j] =
                    __builtin_amdgcn_mfma_f32_16x16x32_bf16(af[i][kk], bf[j][kk], acc[mi0 + i][nj0 + j], 0, 0, 0);
    __builtin_amdgcn_s_setprio(0);
}
__device__ __forceinline__ void stage2(const unsigned short* g, char* dst, int K, int r32, int kn) {
    gl16(g + (size_t)r32 * K + kn, dst);
    gl16(g + (size_t)(r32 + 8) * K + kn, dst + 1024);
}

template<bool OUT_BF16>
__global__ __launch_bounds__(512, 2)
void gemm256(const unsigned short* __restrict__ A,   // [M][K] bf16
             const unsigned short* __restrict__ Bt,  // [N][K] bf16
             void* __restrict__ Cp, int N, int K)
{
    extern __shared__ char lds[];
    const int tid = threadIdx.x;
    const int l   = tid & 63;
    const int l15 = l & 15, lg = l >> 4;
    const int wid = tid >> 6;
    const int wr  = wid >> 2;
    const int wc  = wid & 3;

    // column-slab XCD mapping: XCD owns ntx/8 B-strips, scans by fastest
    // (concurrent blocks within an XCD share B-strips in L2 and A-tiles across XCDs in L3)
    const int nwg = gridDim.x;
    const int bid = blockIdx.x;
    const int ntx = N >> 8;
    const int nty = nwg / ntx;
    const int cpx = ntx >> 3;
    const int xcd = bid & 7;
    const int idx = bid >> 3;
    const int bx = xcd * cpx + idx / nty;
    const int by = idx % nty;
    const int m0 = by * 256, n0 = bx * 256;

    char* const Abase = lds + wr * 16384;
    char* const Bbase = lds + 32768 + (wc >> 1) * 16384 + (wc & 1) * 8192;

    const int l8 = l >> 3, l7 = l & 7;
    const int swslot = (l7 ^ l8) << 3;

    const unsigned short* Ag = A  + (size_t)(m0 + wr * 128 + wc * 16 + l8) * K + swslot;
    const unsigned short* Bg = Bt + (size_t)(n0 + wc * 64 + wr * 16 + l8) * K + swslot;
    char* const Adst = Abase + (wc * 16) * 128 + l * 16;
    char* const Bdst = Bbase + (wr * 16) * 128 + l * 16;

    f32x4 acc[8][4] = {};
    bf16x8 af[4][2], bf[2][2];

    stage2(Ag, Adst, K, 0, 0);
    stage2(Bg, Bdst, K, 0, 0);
    stage2(Ag, Adst + 64 * 128, K, 64, 0);
    stage2(Bg, Bdst + 32 * 128, K, 32, 0);
    VMCNT(0);
    BAR();

    const int NT = K >> 6;
    for (int t = 0; t < NT; ++t) {
        const int cb = (t & 1) * 65536, nb = cb ^ 65536;
        const int kn = (t + 1) << 6;
        const bool hn = (t + 1) < NT;
        lda4(af, Abase + cb, 0, l15, lg);
        ldb2(bf, Bbase + cb, 0, l15, lg);
        if (hn) stage2(Ag, Adst + nb, K, 0, kn);
        BAR();
        mfma16(acc, af, bf, 0, 0);
        VMCNT(4); LGKM0();
        BAR();
        lda4(af, Abase + cb, 1, l15, lg);
        if (hn) stage2(Bg, Bdst + nb, K, 0, kn);
        BAR();
        mfma16(acc, af, bf, 4, 0);
        VMCNT(4); LGKM0();
        BAR();
        ldb2(bf, Bbase + cb, 1, l15, lg);
        if (hn) stage2(Ag, Adst + nb + 64 * 128, K, 64, kn);
        BAR();
        mfma16(acc, af, bf, 4, 2);
        LGKM0();
        BAR();
        lda4(af, Abase + cb, 0, l15, lg);
        if (hn) stage2(Bg, Bdst + nb + 32 * 128, K, 32, kn);
        BAR();
        mfma16(acc, af, bf, 0, 2);
        VMCNT(4); LGKM0();
        BAR();
    }

    const int crow = m0 + wr * 128 + lg * 4;
    const int ccol = n0 + wc * 64 + l15;
    #pragma unroll
    for (int mi = 0; mi < 8; ++mi) {
        #pragma unroll
        for (int nj = 0; nj < 4; ++nj) {
            #pragma unroll
            for (int rr = 0; rr < 4; ++rr) {
                int row = crow + mi * 16 + rr;
                int col = ccol + nj * 16;
                float v = acc[mi][nj][rr];
                if (OUT_BF16) ((unsigned short*)Cp)[(size_t)row * N + col] = f2bf(v);
                else          ((float*)Cp)[(size_t)row * N + col] = v;
            }
        }
    }
}

// ---------------- per-head LayerNorm + RoPE, in place on combined QKV bf16 [S][12288] ----------------
__global__ __launch_bounds__(256)
void ln_rope(unsigned short* __restrict__ QKV,
             const float* __restrict__ qg, const float* __restrict__ qb,
             const float* __restrict__ kg, const float* __restrict__ kb,
             const int* __restrict__ pos)
{
    const int tid = threadIdx.x;
    const int l = tid & 63;
    const int w = tid >> 6;
    const int rid = blockIdx.x * 4 + w;
    const int s = rid >> 6;
    const int hh = rid & 63;
    const int which = hh >> 5;
    const int h = hh & 31;
    unsigned short* p = QKV + (size_t)s * QKV_N + which * HID + h * HD;
    const float* gamma = which ? kg : qg;
    const float* beta  = which ? kb : qb;

    float lo = bf2f(p[l]);
    float hi = bf2f(p[l + 64]);
    float sum = lo + hi;
    #pragma unroll
    for (int off = 32; off >= 1; off >>= 1) sum += __shfl_xor(sum, off, 64);
    float mu = sum * (1.0f / 128.0f);
    float dlo = lo - mu, dhi = hi - mu;
    float vs = dlo * dlo + dhi * dhi;
    #pragma unroll
    for (int off = 32; off >= 1; off >>= 1) vs += __shfl_xor(vs, off, 64);
    float rstd = rsqrtf(vs * (1.0f / 128.0f) + 1e-5f);
    float xlo = dlo * rstd * gamma[l] + beta[l];
    float xhi = dhi * rstd * gamma[l + 64] + beta[l + 64];

    float fpos = (float)pos[s];
    float invf = exp2f(-13.287712379549449f * (float)l * (1.0f / 64.0f));
    float ang = fpos * invf;
    float sn, cs;
    sincosf(ang, &sn, &cs);
    p[l]      = f2bf(xlo * cs - xhi * sn);
    p[l + 64] = f2bf(xhi * cs + xlo * sn);
}

// ---------------- causal flash attention: KVB=64, K & V^T LDS-dbuf via global_load_lds ----------------
#define KVB 64

__global__ __launch_bounds__(256)
void attn_fwd(const unsigned short* __restrict__ QKV,   // [S][12288]
              const unsigned short* __restrict__ Vtg,   // [4096][S]
              unsigned short* __restrict__ O)           // [S][4096]
{
    __shared__ unsigned short Ks[2][KVB * HD];
    __shared__ unsigned short Vs[2][HD * KVB];
    __shared__ unsigned short Ps[4][16 * 72];

    const int tid = threadIdx.x;
    const int l = tid & 63;
    const int w = tid >> 6;
    const int l15 = l & 15, lg = l >> 4;
    const int h = blockIdx.y;
    const int qb = gridDim.x - 1 - blockIdx.x;
    const int q0 = qb * 64;
    const int qw = q0 + w * 16;

    const unsigned short* Qp = QKV + h * HD;
    const unsigned short* Kp = QKV + HID + h * HD;
    const unsigned short* Vp = Vtg + (size_t)h * HD * S_LEN;

    bf16x8 qf[4];
    #pragma unroll
    for (int d = 0; d < 4; ++d)
        qf[d] = *(const bf16x8*)&Qp[(size_t)(qw + l15) * QKV_N + d * 32 + lg * 8];

    f32x4 o_acc[8] = {};
    float mrow[4], lrow[4];
    #pragma unroll
    for (int r = 0; r < 4; ++r) { mrow[r] = -1e30f; lrow[r] = 0.0f; }

    const float scale = 0.08838834764831845f;

    const int ksl = tid & 15;
    const int kr7 = (tid >> 4) & 7;
    const int ksg = (ksl & 8) | ((ksl ^ kr7) & 7);
    const unsigned short* Kg = Kp + (size_t)(tid >> 4) * QKV_N + ksg * 8;
    const int vsg = (tid & 7) ^ ((tid >> 3) & 7);
    const unsigned short* Vg = Vp + (size_t)(tid >> 3) * S_LEN + vsg * 8;

#define STAGE(buf, kv0s) do {                                                          \
    _Pragma("unroll")                                                                  \
    for (int i_ = 0; i_ < 4; ++i_)                                                     \
        gl16(Kg + (size_t)((kv0s) + i_ * 16) * QKV_N,                                  \
             (char*)Ks[buf] + (i_ * 256 + tid) * 16);                                  \
    _Pragma("unroll")                                                                  \
    for (int i_ = 0; i_ < 4; ++i_)                                                     \
        gl16(Vg + (size_t)i_ * 32 * S_LEN + (kv0s),                                    \
             (char*)Vs[buf] + (i_ * 256 + tid) * 16);                                  \
} while (0)

    STAGE(0, 0);
    VMCNT(0);
    __syncthreads();

    const int nt = q0 / KVB + 1;
    for (int t = 0; t < nt; ++t) {
        const int kv0 = t * KVB;
        const int cur = t & 1;
        const bool hn = (t + 1) < nt;
        if (hn) STAGE(cur ^ 1, kv0 + KVB);

        f32x4 sc[4] = {};
        #pragma unroll
        for (int kvf = 0; kvf < 4; ++kvf) {
            int r = kvf * 16 + l15;
            int sw = (r & 7) << 4;
            #pragma unroll
            for (int d = 0; d < 4; ++d) {
                bf16x8 kf = *(const bf16x8*)((const char*)Ks[cur] + r * 256 + ((d * 64 + lg * 16) ^ sw));
                sc[kvf] = __builtin_amdgcn_mfma_f32_16x16x32_bf16(qf[d], kf, sc[kvf], 0, 0, 0);
            }
        }

        const bool full = (kv0 + KVB <= qw);
        #pragma unroll
        for (int r = 0; r < 4; ++r) {
            int qg = qw + lg * 4 + r;
            float s0, s1, s2, s3;
            if (full) {
                s0 = sc[0][r] * scale; s1 = sc[1][r] * scale;
                s2 = sc[2][r] * scale; s3 = sc[3][r] * scale;
            } else {
                s0 = (kv0 + l15      <= qg) ? sc[0][r] * scale : -1e30f;
                s1 = (kv0 + 16 + l15 <= qg) ? sc[1][r] * scale : -1e30f;
                s2 = (kv0 + 32 + l15 <= qg) ? sc[2][r] * scale : -1e30f;
                s3 = (kv0 + 48 + l15 <= qg) ? sc[3][r] * scale : -1e30f;
            }
            float mx = fmaxf(fmaxf(s0, s1), fmaxf(s2, s3));
            #pragma unroll
            for (int off = 8; off >= 1; off >>= 1) mx = fmaxf(mx, __shfl_xor(mx, off, 64));
            float mn = mrow[r];
            if (!__all(mx <= mn + 8.0f)) {
                mn = fmaxf(mn, mx);
                float corr = __expf(mrow[r] - mn);
                lrow[r] *= corr;
                #pragma unroll
                for (int df = 0; df < 8; ++df) o_acc[df][r] *= corr;
                mrow[r] = mn;
            }
            float p0 = __expf(s0 - mn);
            float p1 = __expf(s1 - mn);
            float p2 = __expf(s2 - mn);
            float p3 = __expf(s3 - mn);
            float rs = (p0 + p1) + (p2 + p3);
            #pragma unroll
            for (int off = 8; off >= 1; off >>= 1) rs += __shfl_xor(rs, off, 64);
            lrow[r] += rs;
            int ql = lg * 4 + r;
            Ps[w][ql * 72 + l15]      = f2bf(p0);
            Ps[w][ql * 72 + 16 + l15] = f2bf(p1);
            Ps[w][ql * 72 + 32 + l15] = f2bf(p2);
            Ps[w][ql * 72 + 48 + l15] = f2bf(p3);
        }

        bf16x8 pa0 = *(const bf16x8*)&Ps[w][l15 * 72 + lg * 8];
        bf16x8 pa1 = *(const bf16x8*)&Ps[w][l15 * 72 + 32 + lg * 8];
        #pragma unroll
        for (int df = 0; df < 8; ++df) {
            int d = df * 16 + l15;
            int sw = (d & 7) << 4;
            const char* vrow = (const char*)Vs[cur] + d * 128;
            bf16x8 v0 = *(const bf16x8*)(vrow + ((lg * 16) ^ sw));
            bf16x8 v1 = *(const bf16x8*)(vrow + ((64 + lg * 16) ^ sw));
            o_acc[df] = __builtin_amdgcn_mfma_f32_16x16x32_bf16(pa0, v0, o_acc[df], 0, 0, 0);
            o_acc[df] = __builtin_amdgcn_mfma_f32_16x16x32_bf16(pa1, v1, o_acc[df], 0, 0, 0);
        }

        VMCNT(0);
        BAR();
    }
#undef STAGE

    #pragma unroll
    for (int df = 0; df < 8; ++df) {
        #pragma unroll
        for (int r = 0; r < 4; ++r) {
            int q = qw + lg * 4 + r;
            int d = h * HD + df * 16 + l15;
            O[(size_t)q * HID + d] = f2bf(o_acc[df][r] / lrow[r]);
        }
    }
}

extern "C" void kernel_launch(void* const* d_in, const int* in_sizes, int n_in,
                              void* d_out, int out_size, void* d_ws, size_t ws_size,
                              hipStream_t stream)
{
    (void)in_sizes; (void)n_in; (void)out_size; (void)ws_size;
    const float* X    = (const float*)d_in[0];
    const int*   pos  = (const int*)d_in[1];
    const float* Wq   = (const float*)d_in[2];
    const float* Wk   = (const float*)d_in[3];
    const float* Wv   = (const float*)d_in[4];
    const float* Wo   = (const float*)d_in[5];
    const float* qn_w = (const float*)d_in[6];
    const float* qn_b = (const float*)d_in[7];
    const float* kn_w = (const float*)d_in[8];
    const float* kn_b = (const float*)d_in[9];
    float* out = (float*)d_out;

    unsigned short* Xb    = (unsigned short*)d_ws;
    unsigned short* QKVb  = (unsigned short*)((char*)d_ws + 16777216);
    unsigned short* Wt    = (unsigned short*)((char*)d_ws + 67108864);
    unsigned short* Vtg   = (unsigned short*)((char*)d_ws + 134217728);
    unsigned short* Ab    = Xb;

    {
        auto k1 = gemm256<true>;
        auto k2 = gemm256<false>;
        (void)hipFuncSetAttribute((const void*)k1, hipFuncAttributeMaxDynamicSharedMemorySize, 131072);
        (void)hipFuncSetAttribute((const void*)k2, hipFuncAttributeMaxDynamicSharedMemorySize, 131072);
    }

    dim3 blk(256);

    cvt_f32_bf16<<<dim3((S_LEN * HID / 8 + 255) / 256), blk, 0, stream>>>(X, Xb, S_LEN * HID / 8);

    W3 w3{Wq, Wk, Wv};
    cvt_w_t3<<<dim3(HID / 64, HID / 64, 3), blk, 0, stream>>>(w3, Wt, HID, HID);

    gemm256<true><<<dim3((S_LEN / 256) * (QKV_N / 256)), dim3(512), 131072, stream>>>(Xb, Wt, QKVb, QKV_N, HID);

    v_transpose<<<dim3(S_LEN / 64, HID / 64), blk, 0, stream>>>(QKVb, Vtg);
    ln_rope<<<dim3(S_LEN * 64 / 4), blk, 0, stream>>>(QKVb, qn_w, qn_b, kn_w, kn_b, pos);

    attn_fwd<<<dim3(S_LEN / 64, NH), blk, 0, stream>>>(QKVb, Vtg, Ab);

    W3 wo3{Wo, Wo, Wo};
    cvt_w_t3<<<dim3(HID / 64, HID / 64, 1), blk, 0, stream>>>(wo3, Wt, HID, HID);

    gemm256<false><<<dim3((S_LEN / 256) * (HID / 256)), dim3(512), 131072, stream>>>(Ab, Wt, out, HID, HID);
}